// Round 1
// baseline (1128.403 us; speedup 1.0000x reference)
//
#include <hip/hip_runtime.h>
#include <math.h>

// GConvLSTM single step from zero state + linear head.
// Key simplification: H=C=0 initially => cheb_conv(H)=bh[g], F-gate irrelevant.
// out = (O*tanh(C)) @ lin_w + lin_b with
//   I = sigmoid(chebX_0 + bx0+bh0+bg0)
//   T = tanh   (chebX_2 + bx2+bh2+bg2)
//   C = I*T
//   O = sigmoid(chebX_3 + bx3+bh3+bg3 + wc2*C)
// chebX_g = sum_k Txk @ Wx[g][k],  Tx via prop(t) = segment_sum(norm*t[src], dst)

__global__ void k_deg(const int* __restrict__ src, const float* __restrict__ w,
                      float* __restrict__ deg, int nE) {
    int e = blockIdx.x * blockDim.x + threadIdx.x;
    if (e < nE) atomicAdd(&deg[src[e]], w[e]);
}

__global__ void k_norm(const int* __restrict__ src, const int* __restrict__ dst,
                       const float* __restrict__ w, const float* __restrict__ deg,
                       float* __restrict__ norm, int nE) {
    int e = blockIdx.x * blockDim.x + threadIdx.x;
    if (e >= nE) return;
    float ds = deg[src[e]], dd = deg[dst[e]];
    float a = ds > 0.f ? rsqrtf(ds) : 0.f;
    float b = dd > 0.f ? rsqrtf(dd) : 0.f;
    norm[e] = -a * w[e] * b;
}

__global__ void k_neg(const float4* __restrict__ in, float4* __restrict__ out, int n4) {
    int i = blockIdx.x * blockDim.x + threadIdx.x;
    if (i < n4) {
        float4 v = in[i];
        out[i] = make_float4(-v.x, -v.y, -v.z, -v.w);
    }
}

// out[dst] += scale * norm[e] * t[src], 32 features, 8 threads/edge (float4 each)
__global__ void k_scatter(const float* __restrict__ t, float* __restrict__ out,
                          const int* __restrict__ src, const int* __restrict__ dst,
                          const float* __restrict__ norm, float scale, int nE) {
    int idx = blockIdx.x * blockDim.x + threadIdx.x;
    if (idx >= nE * 8) return;
    int e = idx >> 3, q = idx & 7;
    int s = src[e], d = dst[e];
    float nv = norm[e] * scale;
    const float4 v = *reinterpret_cast<const float4*>(t + (size_t)s * 32 + q * 4);
    float* o = out + (size_t)d * 32 + q * 4;
    atomicAdd(o + 0, nv * v.x);
    atomicAdd(o + 1, nv * v.y);
    atomicAdd(o + 2, nv * v.z);
    atomicAdd(o + 3, nv * v.w);
}

__device__ __forceinline__ float4 ld4(const float* p) {
    return *reinterpret_cast<const float4*>(p);
}
__device__ __forceinline__ void fma4(float4& a, float t, const float4& w) {
    a.x = fmaf(t, w.x, a.x); a.y = fmaf(t, w.y, a.y);
    a.z = fmaf(t, w.z, a.z); a.w = fmaf(t, w.w, a.w);
}
__device__ __forceinline__ float redfs(float v) {
    v += __shfl_xor(v, 16); v += __shfl_xor(v, 32); return v;
}
__device__ __forceinline__ float4 redfs4(float4 v) {
    v.x = redfs(v.x); v.y = redfs(v.y); v.z = redfs(v.z); v.w = redfs(v.w); return v;
}
__device__ __forceinline__ float4 add4(float4 a, float4 b) {
    return make_float4(a.x + b.x, a.y + b.y, a.z + b.z, a.w + b.w);
}
__device__ __forceinline__ float sigf(float x) { return 1.f / (1.f + expf(-x)); }

// Fused gates GEMM + LSTM pointwise + linear head.
// Block = 256 threads (4 waves). Block handles 32 nodes (8 per wave).
// Lane decomposition: fs = lane>>4 (f-slice of 4), hq = lane&15 (h-quad).
__global__ __launch_bounds__(256)
void k_final(const float* __restrict__ tx0, const float* __restrict__ tx1,
             const float* __restrict__ tx2, const float* __restrict__ tx3,
             const float* __restrict__ Wx, const float* __restrict__ bx,
             const float* __restrict__ bh, const float* __restrict__ wc,
             const float* __restrict__ bg, const float* __restrict__ lin_w,
             const float* __restrict__ lin_b, float* __restrict__ out, int N) {
    __shared__ float rows[32][128];
    const int tid = threadIdx.x;
    const int base = blockIdx.x * 32;

    // stage Tx rows: 32 nodes x 128 features
    for (int i = tid; i < 32 * 128; i += 256) {
        int nl = i >> 7, f = i & 127;
        int n = base + nl;
        float v = 0.f;
        if (n < N) {
            int f5 = f >> 5;
            const float* bp = (f5 == 0) ? tx0 : (f5 == 1) ? tx1 : (f5 == 2) ? tx2 : tx3;
            v = bp[(size_t)n * 32 + (f & 31)];
        }
        rows[nl][f] = v;
    }
    __syncthreads();

    const int wave = tid >> 6, lane = tid & 63;
    const int fs = lane >> 4, hq = lane & 15;
    const float* WI = Wx + 0 * 8192;  // gate i
    const float* WC = Wx + 2 * 8192;  // gate c
    const float* WO = Wx + 3 * 8192;  // gate o

    float4 accI[8], accC[8], accO[8];
#pragma unroll
    for (int j = 0; j < 8; ++j) {
        accI[j] = make_float4(0, 0, 0, 0);
        accC[j] = make_float4(0, 0, 0, 0);
        accO[j] = make_float4(0, 0, 0, 0);
    }

    for (int cb = 0; cb < 32; ++cb) {
        int f = cb * 4 + fs;
        int wo = f * 64 + hq * 4;
        float4 wi = ld4(WI + wo);
        float4 wcg = ld4(WC + wo);
        float4 wog = ld4(WO + wo);
#pragma unroll
        for (int j = 0; j < 8; ++j) {
            float t = rows[wave * 8 + j][f];
            fma4(accI[j], t, wi);
            fma4(accC[j], t, wcg);
            fma4(accO[j], t, wog);
        }
    }

    // biases (gate totals: bx + bh + bg)
    const int ho = hq * 4;
    const float4 bI4 = add4(add4(ld4(bx + 0 * 64 + ho), ld4(bh + 0 * 64 + ho)), ld4(bg + 0 * 64 + ho));
    const float4 bC4 = add4(add4(ld4(bx + 2 * 64 + ho), ld4(bh + 2 * 64 + ho)), ld4(bg + 2 * 64 + ho));
    const float4 bO4 = add4(add4(ld4(bx + 3 * 64 + ho), ld4(bh + 3 * 64 + ho)), ld4(bg + 3 * 64 + ho));
    const float4 wc2 = ld4(wc + 2 * 64 + ho);
    const float4 lw = ld4(lin_w + ho);
    const float lb = lin_b[0];

#pragma unroll
    for (int j = 0; j < 8; ++j) {
        float4 ai = redfs4(accI[j]);
        float4 ac = redfs4(accC[j]);
        float4 ao = redfs4(accO[j]);
        int n = base + wave * 8 + j;

        float4 I = make_float4(sigf(ai.x + bI4.x), sigf(ai.y + bI4.y),
                               sigf(ai.z + bI4.z), sigf(ai.w + bI4.w));
        float4 T = make_float4(tanhf(ac.x + bC4.x), tanhf(ac.y + bC4.y),
                               tanhf(ac.z + bC4.z), tanhf(ac.w + bC4.w));
        float4 C = make_float4(I.x * T.x, I.y * T.y, I.z * T.z, I.w * T.w);
        float4 O = make_float4(sigf(ao.x + bO4.x + wc2.x * C.x),
                               sigf(ao.y + bO4.y + wc2.y * C.y),
                               sigf(ao.z + bO4.z + wc2.z * C.z),
                               sigf(ao.w + bO4.w + wc2.w * C.w));
        float4 H = make_float4(O.x * tanhf(C.x), O.y * tanhf(C.y),
                               O.z * tanhf(C.z), O.w * tanhf(C.w));
        float p = H.x * lw.x + H.y * lw.y + H.z * lw.z + H.w * lw.w;
        p += __shfl_xor(p, 1);
        p += __shfl_xor(p, 2);
        p += __shfl_xor(p, 4);
        p += __shfl_xor(p, 8);
        if (lane == 0 && n < N) out[n] = p + lb;
    }
}

extern "C" void kernel_launch(void* const* d_in, const int* in_sizes, int n_in,
                              void* d_out, int out_size, void* d_ws, size_t ws_size,
                              hipStream_t stream) {
    const float* x   = (const float*)d_in[0];
    const int*   ei  = (const int*)d_in[1];
    const float* ew  = (const float*)d_in[2];
    const float* Wx  = (const float*)d_in[3];
    const float* bx  = (const float*)d_in[4];
    // d_in[5] = Wh (unused: zero initial state)
    const float* bh  = (const float*)d_in[6];
    const float* wcp = (const float*)d_in[7];
    const float* bg  = (const float*)d_in[8];
    const float* lw  = (const float*)d_in[9];
    const float* lb  = (const float*)d_in[10];
    float* out = (float*)d_out;

    const int N  = in_sizes[0] / 32;
    const int nE = in_sizes[2];
    const int* src = ei;
    const int* dst = ei + nE;

    char* ws = (char*)d_ws;
    size_t off = 0;
    float* norm = (float*)(ws + off); off += (size_t)nE * 4;
    float* deg  = (float*)(ws + off); off += (size_t)N * 4;
    float* Tx1  = (float*)(ws + off); off += (size_t)N * 32 * 4;
    float* Tx2  = (float*)(ws + off); off += (size_t)N * 32 * 4;
    float* Tx3  = (float*)(ws + off); off += (size_t)N * 32 * 4;

    hipMemsetAsync(deg, 0, (size_t)N * 4, stream);
    hipMemsetAsync(Tx1, 0, (size_t)N * 32 * 4, stream);

    const int eb = (nE + 255) / 256;
    k_deg<<<eb, 256, 0, stream>>>(src, ew, deg, nE);
    k_norm<<<eb, 256, 0, stream>>>(src, dst, ew, deg, norm, nE);

    const int n4 = N * 8;  // N*32/4
    const int nb = (n4 + 255) / 256;
    // Tx2 pre-init = -Tx0 (x); Tx3 pre-init = -Tx1 (after Tx1 ready)
    k_neg<<<nb, 256, 0, stream>>>((const float4*)x, (float4*)Tx2, n4);

    const int sb = (nE * 8 + 255) / 256;
    k_scatter<<<sb, 256, 0, stream>>>(x, Tx1, src, dst, norm, 1.f, nE);   // Tx1 = prop(x)
    k_neg<<<nb, 256, 0, stream>>>((const float4*)Tx1, (float4*)Tx3, n4);
    k_scatter<<<sb, 256, 0, stream>>>(Tx1, Tx2, src, dst, norm, 2.f, nE); // Tx2 = 2*prop(Tx1) - x
    k_scatter<<<sb, 256, 0, stream>>>(Tx2, Tx3, src, dst, norm, 2.f, nE); // Tx3 = 2*prop(Tx2) - Tx1

    const int fb = (N + 31) / 32;
    k_final<<<fb, 256, 0, stream>>>(x, Tx1, Tx2, Tx3, Wx, bx, bh, wcp, bg,
                                    lw, lb, out, N);
}

// Round 2
// 308.741 us; speedup vs baseline: 3.6549x; 3.6549x over previous
//
#include <hip/hip_runtime.h>
#include <math.h>

// GConvLSTM single step from zero state + linear head.
// H=C=0 initially => cheb_conv(H)=bh[g], F-gate irrelevant.
//   I = sigmoid(chebX_0 + bx0+bh0+bg0)
//   T = tanh   (chebX_2 + bx2+bh2+bg2)
//   C = I*T
//   O = sigmoid(chebX_3 + bx3+bh3+bg3 + wc2*C)
//   out = (O*tanh(C)) @ lin_w + lin_b
// chebX_g = sum_k Txk @ Wx[g][k],  Tx via prop(t) = segment_sum(norm*t[src], dst)
//
// R2: push->pull. Build CSR by dst on device each call (int atomics only),
// then 3 gather passes (no float atomics, no 400MB atomic write-through).

#define NT 256

__global__ void k_deg_hist(const int* __restrict__ src, const int* __restrict__ dst,
                           const float* __restrict__ w, float* __restrict__ deg,
                           int* __restrict__ cnt, int nE) {
    int e = blockIdx.x * blockDim.x + threadIdx.x;
    if (e >= nE) return;
    atomicAdd(&deg[src[e]], w[e]);
    atomicAdd(&cnt[dst[e]], 1);
}

// block-local exclusive scan of cnt -> rowptr, block sums -> partials
__global__ void k_scanA(const int* __restrict__ cnt, int* __restrict__ rowptr,
                        int* __restrict__ partials, int N) {
    __shared__ int s[NT];
    int t = threadIdx.x, i = blockIdx.x * NT + t;
    int v = (i < N) ? cnt[i] : 0;
    s[t] = v;
    __syncthreads();
    for (int off = 1; off < NT; off <<= 1) {
        int u = (t >= off) ? s[t - off] : 0;
        __syncthreads();
        s[t] += u;
        __syncthreads();
    }
    if (i < N) rowptr[i] = s[t] - v;  // exclusive within block
    if (t == NT - 1) partials[blockIdx.x] = s[t];
}

// single-block exclusive scan of partials (nb <= 1024)
__global__ void k_scanB(int* __restrict__ partials, int nb) {
    __shared__ int s[1024];
    int t = threadIdx.x;
    int v = (t < nb) ? partials[t] : 0;
    s[t] = v;
    __syncthreads();
    for (int off = 1; off < 1024; off <<= 1) {
        int u = (t >= off) ? s[t - off] : 0;
        __syncthreads();
        s[t] += u;
        __syncthreads();
    }
    if (t < nb) partials[t] = s[t] - v;
}

__global__ void k_scanC(int* __restrict__ rowptr, const int* __restrict__ partials,
                        int* __restrict__ cursor, int N) {
    int i = blockIdx.x * NT + threadIdx.x;
    if (i >= N) return;
    int v = rowptr[i] + partials[blockIdx.x];
    rowptr[i] = v;
    cursor[i] = v;
}

// place {src, norm} entries into dst-grouped CSR slots (int atomics only)
__global__ void k_fill(const int* __restrict__ src, const int* __restrict__ dst,
                       const float* __restrict__ w, const float* __restrict__ deg,
                       int* __restrict__ cursor, int2* __restrict__ entries, int nE) {
    int e = blockIdx.x * blockDim.x + threadIdx.x;
    if (e >= nE) return;
    int s = src[e], d = dst[e];
    float ds = deg[s], dd = deg[d];
    float a = ds > 0.f ? rsqrtf(ds) : 0.f;
    float b = dd > 0.f ? rsqrtf(dd) : 0.f;
    float nv = -a * w[e] * b;
    int pos = atomicAdd(&cursor[d], 1);
    entries[pos] = make_int2(s, __float_as_int(nv));
}

// out[n][f] = scale * sum_{e in CSR[n]} norm_e * t[src_e][f]  -  sub[n][f]
__global__ __launch_bounds__(256)
void k_gather(const float* __restrict__ t, const float* __restrict__ sub,
              float* __restrict__ out, const int* __restrict__ rowptr,
              const int* __restrict__ cnt, const int2* __restrict__ entries,
              float scale, int N) {
    int idx = blockIdx.x * blockDim.x + threadIdx.x;
    if (idx >= N * 32) return;
    int n = idx >> 5, f = idx & 31;
    int beg = rowptr[n], end = beg + cnt[n];
    float acc0 = 0.f, acc1 = 0.f;
    int i = beg;
    for (; i + 1 < end; i += 2) {
        int2 e0 = entries[i];
        int2 e1 = entries[i + 1];
        float v0 = t[(size_t)e0.x * 32 + f];
        float v1 = t[(size_t)e1.x * 32 + f];
        acc0 = fmaf(__int_as_float(e0.y), v0, acc0);
        acc1 = fmaf(__int_as_float(e1.y), v1, acc1);
    }
    if (i < end) {
        int2 e0 = entries[i];
        acc0 = fmaf(__int_as_float(e0.y), t[(size_t)e0.x * 32 + f], acc0);
    }
    float s = sub ? sub[idx] : 0.f;
    out[idx] = fmaf(scale, acc0 + acc1, -s);
}

__device__ __forceinline__ float4 ld4(const float* p) {
    return *reinterpret_cast<const float4*>(p);
}
__device__ __forceinline__ void fma4(float4& a, float t, const float4& w) {
    a.x = fmaf(t, w.x, a.x); a.y = fmaf(t, w.y, a.y);
    a.z = fmaf(t, w.z, a.z); a.w = fmaf(t, w.w, a.w);
}
__device__ __forceinline__ float redfs(float v) {
    v += __shfl_xor(v, 16); v += __shfl_xor(v, 32); return v;
}
__device__ __forceinline__ float4 redfs4(float4 v) {
    v.x = redfs(v.x); v.y = redfs(v.y); v.z = redfs(v.z); v.w = redfs(v.w); return v;
}
__device__ __forceinline__ float4 add4(float4 a, float4 b) {
    return make_float4(a.x + b.x, a.y + b.y, a.z + b.z, a.w + b.w);
}
__device__ __forceinline__ float sigf(float x) { return 1.f / (1.f + expf(-x)); }

// Fused gates GEMM + LSTM pointwise + linear head.
// Block = 256 threads (4 waves), 32 nodes/block (8 per wave).
__global__ __launch_bounds__(256)
void k_final(const float* __restrict__ tx0, const float* __restrict__ tx1,
             const float* __restrict__ tx2, const float* __restrict__ tx3,
             const float* __restrict__ Wx, const float* __restrict__ bx,
             const float* __restrict__ bh, const float* __restrict__ wc,
             const float* __restrict__ bg, const float* __restrict__ lin_w,
             const float* __restrict__ lin_b, float* __restrict__ out, int N) {
    __shared__ float rows[32][128];
    const int tid = threadIdx.x;
    const int base = blockIdx.x * 32;

    for (int i = tid; i < 32 * 128; i += 256) {
        int nl = i >> 7, f = i & 127;
        int n = base + nl;
        float v = 0.f;
        if (n < N) {
            int f5 = f >> 5;
            const float* bp = (f5 == 0) ? tx0 : (f5 == 1) ? tx1 : (f5 == 2) ? tx2 : tx3;
            v = bp[(size_t)n * 32 + (f & 31)];
        }
        rows[nl][f] = v;
    }
    __syncthreads();

    const int wave = tid >> 6, lane = tid & 63;
    const int fs = lane >> 4, hq = lane & 15;
    const float* WI = Wx + 0 * 8192;
    const float* WC = Wx + 2 * 8192;
    const float* WO = Wx + 3 * 8192;

    float4 accI[8], accC[8], accO[8];
#pragma unroll
    for (int j = 0; j < 8; ++j) {
        accI[j] = make_float4(0, 0, 0, 0);
        accC[j] = make_float4(0, 0, 0, 0);
        accO[j] = make_float4(0, 0, 0, 0);
    }

    for (int cb = 0; cb < 32; ++cb) {
        int f = cb * 4 + fs;
        int wo = f * 64 + hq * 4;
        float4 wi = ld4(WI + wo);
        float4 wcg = ld4(WC + wo);
        float4 wog = ld4(WO + wo);
#pragma unroll
        for (int j = 0; j < 8; ++j) {
            float t = rows[wave * 8 + j][f];
            fma4(accI[j], t, wi);
            fma4(accC[j], t, wcg);
            fma4(accO[j], t, wog);
        }
    }

    const int ho = hq * 4;
    const float4 bI4 = add4(add4(ld4(bx + 0 * 64 + ho), ld4(bh + 0 * 64 + ho)), ld4(bg + 0 * 64 + ho));
    const float4 bC4 = add4(add4(ld4(bx + 2 * 64 + ho), ld4(bh + 2 * 64 + ho)), ld4(bg + 2 * 64 + ho));
    const float4 bO4 = add4(add4(ld4(bx + 3 * 64 + ho), ld4(bh + 3 * 64 + ho)), ld4(bg + 3 * 64 + ho));
    const float4 wc2 = ld4(wc + 2 * 64 + ho);
    const float4 lw = ld4(lin_w + ho);
    const float lb = lin_b[0];

#pragma unroll
    for (int j = 0; j < 8; ++j) {
        float4 ai = redfs4(accI[j]);
        float4 ac = redfs4(accC[j]);
        float4 ao = redfs4(accO[j]);
        int n = base + wave * 8 + j;

        float4 I = make_float4(sigf(ai.x + bI4.x), sigf(ai.y + bI4.y),
                               sigf(ai.z + bI4.z), sigf(ai.w + bI4.w));
        float4 T = make_float4(tanhf(ac.x + bC4.x), tanhf(ac.y + bC4.y),
                               tanhf(ac.z + bC4.z), tanhf(ac.w + bC4.w));
        float4 C = make_float4(I.x * T.x, I.y * T.y, I.z * T.z, I.w * T.w);
        float4 O = make_float4(sigf(ao.x + bO4.x + wc2.x * C.x),
                               sigf(ao.y + bO4.y + wc2.y * C.y),
                               sigf(ao.z + bO4.z + wc2.z * C.z),
                               sigf(ao.w + bO4.w + wc2.w * C.w));
        float4 H = make_float4(O.x * tanhf(C.x), O.y * tanhf(C.y),
                               O.z * tanhf(C.z), O.w * tanhf(C.w));
        float p = H.x * lw.x + H.y * lw.y + H.z * lw.z + H.w * lw.w;
        p += __shfl_xor(p, 1);
        p += __shfl_xor(p, 2);
        p += __shfl_xor(p, 4);
        p += __shfl_xor(p, 8);
        if (lane == 0 && n < N) out[n] = p + lb;
    }
}

extern "C" void kernel_launch(void* const* d_in, const int* in_sizes, int n_in,
                              void* d_out, int out_size, void* d_ws, size_t ws_size,
                              hipStream_t stream) {
    const float* x   = (const float*)d_in[0];
    const int*   ei  = (const int*)d_in[1];
    const float* ew  = (const float*)d_in[2];
    const float* Wx  = (const float*)d_in[3];
    const float* bx  = (const float*)d_in[4];
    // d_in[5] = Wh (unused: zero initial state)
    const float* bh  = (const float*)d_in[6];
    const float* wcp = (const float*)d_in[7];
    const float* bg  = (const float*)d_in[8];
    const float* lw  = (const float*)d_in[9];
    const float* lb  = (const float*)d_in[10];
    float* out = (float*)d_out;

    const int N  = in_sizes[0] / 32;
    const int nE = in_sizes[2];
    const int* src = ei;
    const int* dst = ei + nE;

    char* ws = (char*)d_ws;
    size_t off = 0;
    float* deg     = (float*)(ws + off); off += (size_t)N * 4;
    int*   cnt     = (int*)(ws + off);   off += (size_t)N * 4;
    int*   rowptr  = (int*)(ws + off);   off += (size_t)N * 4;
    int*   cursor  = (int*)(ws + off);   off += (size_t)N * 4;
    int*   partials= (int*)(ws + off);   off += 1024 * 4;
    int2*  entries = (int2*)(ws + off);  off += (size_t)nE * 8;
    float* Tx1     = (float*)(ws + off); off += (size_t)N * 32 * 4;
    float* Tx2     = (float*)(ws + off); off += (size_t)N * 32 * 4;
    float* Tx3     = (float*)(ws + off); off += (size_t)N * 32 * 4;

    hipMemsetAsync(deg, 0, (size_t)N * 4, stream);
    hipMemsetAsync(cnt, 0, (size_t)N * 4, stream);

    const int eb = (nE + NT - 1) / NT;
    const int nb = (N + NT - 1) / NT;

    k_deg_hist<<<eb, NT, 0, stream>>>(src, dst, ew, deg, cnt, nE);
    k_scanA<<<nb, NT, 0, stream>>>(cnt, rowptr, partials, N);
    k_scanB<<<1, 1024, 0, stream>>>(partials, nb);
    k_scanC<<<nb, NT, 0, stream>>>(rowptr, partials, cursor, N);
    k_fill<<<eb, NT, 0, stream>>>(src, dst, ew, deg, cursor, entries, nE);

    const int gb = (N * 32 + NT - 1) / NT;
    k_gather<<<gb, NT, 0, stream>>>(x,   nullptr, Tx1, rowptr, cnt, entries, 1.f, N);
    k_gather<<<gb, NT, 0, stream>>>(Tx1, x,       Tx2, rowptr, cnt, entries, 2.f, N);
    k_gather<<<gb, NT, 0, stream>>>(Tx2, Tx1,     Tx3, rowptr, cnt, entries, 2.f, N);

    const int fb = (N + 31) / 32;
    k_final<<<fb, NT, 0, stream>>>(x, Tx1, Tx2, Tx3, Wx, bx, bh, wcp, bg,
                                   lw, lb, out, N);
}

// Round 3
// 295.630 us; speedup vs baseline: 3.8169x; 1.0443x over previous
//
#include <hip/hip_runtime.h>
#include <math.h>

// GConvLSTM single step from zero state + linear head.
// H=C=0 initially => cheb_conv(H)=bh[g], F-gate irrelevant.
//   I = sigmoid(chebX_0 + bx0+bh0+bg0)
//   T = tanh   (chebX_2 + bx2+bh2+bg2)
//   C = I*T
//   O = sigmoid(chebX_3 + bx3+bh3+bg3 + wc2*C)
//   out = (O*tanh(C)) @ lin_w + lin_b
// chebX_g = sum_k Txk @ Wx[g][k],  Tx via prop(t) = segment_sum(norm*t[src], dst)
//
// R2: push->pull CSR gather (no float atomics).
// R3: k_final epilogue — hw exp2/rcp transcendentals (v_exp_f32+v_rcp_f32)
//     and per-lane single-h gate math (kills the 4x fs-group redundancy).

#define NT 256

__global__ void k_deg_hist(const int* __restrict__ src, const int* __restrict__ dst,
                           const float* __restrict__ w, float* __restrict__ deg,
                           int* __restrict__ cnt, int nE) {
    int e = blockIdx.x * blockDim.x + threadIdx.x;
    if (e >= nE) return;
    atomicAdd(&deg[src[e]], w[e]);
    atomicAdd(&cnt[dst[e]], 1);
}

// block-local exclusive scan of cnt -> rowptr, block sums -> partials
__global__ void k_scanA(const int* __restrict__ cnt, int* __restrict__ rowptr,
                        int* __restrict__ partials, int N) {
    __shared__ int s[NT];
    int t = threadIdx.x, i = blockIdx.x * NT + t;
    int v = (i < N) ? cnt[i] : 0;
    s[t] = v;
    __syncthreads();
    for (int off = 1; off < NT; off <<= 1) {
        int u = (t >= off) ? s[t - off] : 0;
        __syncthreads();
        s[t] += u;
        __syncthreads();
    }
    if (i < N) rowptr[i] = s[t] - v;  // exclusive within block
    if (t == NT - 1) partials[blockIdx.x] = s[t];
}

// single-block exclusive scan of partials (nb <= 1024)
__global__ void k_scanB(int* __restrict__ partials, int nb) {
    __shared__ int s[1024];
    int t = threadIdx.x;
    int v = (t < nb) ? partials[t] : 0;
    s[t] = v;
    __syncthreads();
    for (int off = 1; off < 1024; off <<= 1) {
        int u = (t >= off) ? s[t - off] : 0;
        __syncthreads();
        s[t] += u;
        __syncthreads();
    }
    if (t < nb) partials[t] = s[t] - v;
}

__global__ void k_scanC(int* __restrict__ rowptr, const int* __restrict__ partials,
                        int* __restrict__ cursor, int N) {
    int i = blockIdx.x * NT + threadIdx.x;
    if (i >= N) return;
    int v = rowptr[i] + partials[blockIdx.x];
    rowptr[i] = v;
    cursor[i] = v;
}

// place {src, norm} entries into dst-grouped CSR slots (int atomics only)
__global__ void k_fill(const int* __restrict__ src, const int* __restrict__ dst,
                       const float* __restrict__ w, const float* __restrict__ deg,
                       int* __restrict__ cursor, int2* __restrict__ entries, int nE) {
    int e = blockIdx.x * blockDim.x + threadIdx.x;
    if (e >= nE) return;
    int s = src[e], d = dst[e];
    float ds = deg[s], dd = deg[d];
    float a = ds > 0.f ? rsqrtf(ds) : 0.f;
    float b = dd > 0.f ? rsqrtf(dd) : 0.f;
    float nv = -a * w[e] * b;
    int pos = atomicAdd(&cursor[d], 1);
    entries[pos] = make_int2(s, __float_as_int(nv));
}

// out[n][f] = scale * sum_{e in CSR[n]} norm_e * t[src_e][f]  -  sub[n][f]
__global__ __launch_bounds__(256)
void k_gather(const float* __restrict__ t, const float* __restrict__ sub,
              float* __restrict__ out, const int* __restrict__ rowptr,
              const int* __restrict__ cnt, const int2* __restrict__ entries,
              float scale, int N) {
    int idx = blockIdx.x * blockDim.x + threadIdx.x;
    if (idx >= N * 32) return;
    int n = idx >> 5, f = idx & 31;
    int beg = rowptr[n], end = beg + cnt[n];
    float acc0 = 0.f, acc1 = 0.f;
    int i = beg;
    for (; i + 1 < end; i += 2) {
        int2 e0 = entries[i];
        int2 e1 = entries[i + 1];
        float v0 = t[(size_t)e0.x * 32 + f];
        float v1 = t[(size_t)e1.x * 32 + f];
        acc0 = fmaf(__int_as_float(e0.y), v0, acc0);
        acc1 = fmaf(__int_as_float(e1.y), v1, acc1);
    }
    if (i < end) {
        int2 e0 = entries[i];
        acc0 = fmaf(__int_as_float(e0.y), t[(size_t)e0.x * 32 + f], acc0);
    }
    float s = sub ? sub[idx] : 0.f;
    out[idx] = fmaf(scale, acc0 + acc1, -s);
}

__device__ __forceinline__ float4 ld4(const float* p) {
    return *reinterpret_cast<const float4*>(p);
}
__device__ __forceinline__ void fma4(float4& a, float t, const float4& w) {
    a.x = fmaf(t, w.x, a.x); a.y = fmaf(t, w.y, a.y);
    a.z = fmaf(t, w.z, a.z); a.w = fmaf(t, w.w, a.w);
}
__device__ __forceinline__ float redfs(float v) {
    v += __shfl_xor(v, 16); v += __shfl_xor(v, 32); return v;
}
__device__ __forceinline__ float4 redfs4(float4 v) {
    v.x = redfs(v.x); v.y = redfs(v.y); v.z = redfs(v.z); v.w = redfs(v.w); return v;
}
__device__ __forceinline__ float4 add4(float4 a, float4 b) {
    return make_float4(a.x + b.x, a.y + b.y, a.z + b.z, a.w + b.w);
}
// fast hw transcendentals: v_exp_f32 (2^x) + v_rcp_f32, ~1 ulp each.
__device__ __forceinline__ float sigf(float x) {
    return __builtin_amdgcn_rcpf(1.f + __builtin_amdgcn_exp2f(-1.4426950408889634f * x));
}
__device__ __forceinline__ float tanhf_fast(float x) {
    // 1 - 2/(exp2(2x*log2e)+1); saturates to +/-1 correctly (inf -> 1, 0 -> -1)
    float e = __builtin_amdgcn_exp2f(2.8853900817779268f * x);
    return 1.f - 2.f * __builtin_amdgcn_rcpf(e + 1.f);
}
// static-index 4-way component select (3 v_cndmask, no scratch)
__device__ __forceinline__ float sel(float4 v, int g) {
    float r = v.x;
    r = (g == 1) ? v.y : r;
    r = (g == 2) ? v.z : r;
    r = (g == 3) ? v.w : r;
    return r;
}

// Fused gates GEMM + LSTM pointwise + linear head.
// Block = 256 threads (4 waves), 32 nodes/block (8 per wave).
// Lane decomposition: fs = lane>>4 (f-slice of 4), hq = lane&15 (h-quad).
// Epilogue: lane handles single h = hq*4+fs (no fs-group redundancy).
__global__ __launch_bounds__(256)
void k_final(const float* __restrict__ tx0, const float* __restrict__ tx1,
             const float* __restrict__ tx2, const float* __restrict__ tx3,
             const float* __restrict__ Wx, const float* __restrict__ bx,
             const float* __restrict__ bh, const float* __restrict__ wc,
             const float* __restrict__ bg, const float* __restrict__ lin_w,
             const float* __restrict__ lin_b, float* __restrict__ out, int N) {
    __shared__ float rows[32][128];
    const int tid = threadIdx.x;
    const int base = blockIdx.x * 32;

    for (int i = tid; i < 32 * 128; i += 256) {
        int nl = i >> 7, f = i & 127;
        int n = base + nl;
        float v = 0.f;
        if (n < N) {
            int f5 = f >> 5;
            const float* bp = (f5 == 0) ? tx0 : (f5 == 1) ? tx1 : (f5 == 2) ? tx2 : tx3;
            v = bp[(size_t)n * 32 + (f & 31)];
        }
        rows[nl][f] = v;
    }
    __syncthreads();

    const int wave = tid >> 6, lane = tid & 63;
    const int fs = lane >> 4, hq = lane & 15;
    const float* WI = Wx + 0 * 8192;
    const float* WC = Wx + 2 * 8192;
    const float* WO = Wx + 3 * 8192;

    float4 accI[8], accC[8], accO[8];
#pragma unroll
    for (int j = 0; j < 8; ++j) {
        accI[j] = make_float4(0, 0, 0, 0);
        accC[j] = make_float4(0, 0, 0, 0);
        accO[j] = make_float4(0, 0, 0, 0);
    }

    for (int cb = 0; cb < 32; ++cb) {
        int f = cb * 4 + fs;
        int wo = f * 64 + hq * 4;
        float4 wi = ld4(WI + wo);
        float4 wcg = ld4(WC + wo);
        float4 wog = ld4(WO + wo);
#pragma unroll
        for (int j = 0; j < 8; ++j) {
            float t = rows[wave * 8 + j][f];
            fma4(accI[j], t, wi);
            fma4(accC[j], t, wcg);
            fma4(accO[j], t, wog);
        }
    }

    // per-lane scalar bias/weight for h = hq*4 + fs
    const int ho = hq * 4;
    const float bI = sel(add4(add4(ld4(bx + 0 * 64 + ho), ld4(bh + 0 * 64 + ho)),
                              ld4(bg + 0 * 64 + ho)), fs);
    const float bC = sel(add4(add4(ld4(bx + 2 * 64 + ho), ld4(bh + 2 * 64 + ho)),
                              ld4(bg + 2 * 64 + ho)), fs);
    const float bO = sel(add4(add4(ld4(bx + 3 * 64 + ho), ld4(bh + 3 * 64 + ho)),
                              ld4(bg + 3 * 64 + ho)), fs);
    const float wc2s = sel(ld4(wc + 2 * 64 + ho), fs);
    const float lws = sel(ld4(lin_w + ho), fs);
    const float lb = lin_b[0];

#pragma unroll
    for (int j = 0; j < 8; ++j) {
        // cross-fs reduction (all lanes participate), then each lane keeps
        // only its own h component
        float ai = sel(redfs4(accI[j]), fs);
        float ac = sel(redfs4(accC[j]), fs);
        float ao = sel(redfs4(accO[j]), fs);

        float I = sigf(ai + bI);
        float T = tanhf_fast(ac + bC);
        float C = I * T;
        float O = sigf(ao + bO + wc2s * C);
        float H = O * tanhf_fast(C);

        float p = H * lws;
        p += __shfl_xor(p, 1);
        p += __shfl_xor(p, 2);
        p += __shfl_xor(p, 4);
        p += __shfl_xor(p, 8);
        p += __shfl_xor(p, 16);
        p += __shfl_xor(p, 32);
        int n = base + wave * 8 + j;
        if (lane == 0 && n < N) out[n] = p + lb;
    }
}

extern "C" void kernel_launch(void* const* d_in, const int* in_sizes, int n_in,
                              void* d_out, int out_size, void* d_ws, size_t ws_size,
                              hipStream_t stream) {
    const float* x   = (const float*)d_in[0];
    const int*   ei  = (const int*)d_in[1];
    const float* ew  = (const float*)d_in[2];
    const float* Wx  = (const float*)d_in[3];
    const float* bx  = (const float*)d_in[4];
    // d_in[5] = Wh (unused: zero initial state)
    const float* bh  = (const float*)d_in[6];
    const float* wcp = (const float*)d_in[7];
    const float* bg  = (const float*)d_in[8];
    const float* lw  = (const float*)d_in[9];
    const float* lb  = (const float*)d_in[10];
    float* out = (float*)d_out;

    const int N  = in_sizes[0] / 32;
    const int nE = in_sizes[2];
    const int* src = ei;
    const int* dst = ei + nE;

    char* ws = (char*)d_ws;
    size_t off = 0;
    float* deg     = (float*)(ws + off); off += (size_t)N * 4;
    int*   cnt     = (int*)(ws + off);   off += (size_t)N * 4;
    int*   rowptr  = (int*)(ws + off);   off += (size_t)N * 4;
    int*   cursor  = (int*)(ws + off);   off += (size_t)N * 4;
    int*   partials= (int*)(ws + off);   off += 1024 * 4;
    int2*  entries = (int2*)(ws + off);  off += (size_t)nE * 8;
    float* Tx1     = (float*)(ws + off); off += (size_t)N * 32 * 4;
    float* Tx2     = (float*)(ws + off); off += (size_t)N * 32 * 4;
    float* Tx3     = (float*)(ws + off); off += (size_t)N * 32 * 4;

    hipMemsetAsync(deg, 0, (size_t)N * 4, stream);
    hipMemsetAsync(cnt, 0, (size_t)N * 4, stream);

    const int eb = (nE + NT - 1) / NT;
    const int nb = (N + NT - 1) / NT;

    k_deg_hist<<<eb, NT, 0, stream>>>(src, dst, ew, deg, cnt, nE);
    k_scanA<<<nb, NT, 0, stream>>>(cnt, rowptr, partials, N);
    k_scanB<<<1, 1024, 0, stream>>>(partials, nb);
    k_scanC<<<nb, NT, 0, stream>>>(rowptr, partials, cursor, N);
    k_fill<<<eb, NT, 0, stream>>>(src, dst, ew, deg, cursor, entries, nE);

    const int gb = (N * 32 + NT - 1) / NT;
    k_gather<<<gb, NT, 0, stream>>>(x,   nullptr, Tx1, rowptr, cnt, entries, 1.f, N);
    k_gather<<<gb, NT, 0, stream>>>(Tx1, x,       Tx2, rowptr, cnt, entries, 2.f, N);
    k_gather<<<gb, NT, 0, stream>>>(Tx2, Tx1,     Tx3, rowptr, cnt, entries, 2.f, N);

    const int fb = (N + 31) / 32;
    k_final<<<fb, NT, 0, stream>>>(x, Tx1, Tx2, Tx3, Wx, bx, bh, wcp, bg,
                                   lw, lb, out, N);
}

// Round 4
// 256.878 us; speedup vs baseline: 4.3928x; 1.1509x over previous
//
#include <hip/hip_runtime.h>
#include <math.h>

// GConvLSTM single step from zero state + linear head.
// H=C=0 initially => cheb_conv(H)=bh[g], F-gate irrelevant.
//   I = sigmoid(chebX_0 + bx0+bh0+bg0)
//   T = tanh   (chebX_2 + bx2+bh2+bg2)
//   C = I*T
//   O = sigmoid(chebX_3 + bx3+bh3+bg3 + wc2*C)
//   out = (O*tanh(C)) @ lin_w + lin_b
//
// R2: push->pull CSR gather (no float atomics).
// R3: hw transcendentals + per-lane single-h epilogue.
// R4: 8-replica deg/cnt histograms (contention /8) + dinv precompute;
//     k_final 64-node tile + weight prefetch (halve L2 weight traffic);
//     k_gather float4 per thread.

#define NT 256
#define NREP 8

__global__ void k_deg_hist(const int* __restrict__ src, const int* __restrict__ dst,
                           const float* __restrict__ w, float* __restrict__ degR,
                           int* __restrict__ cntR, int nE, int N) {
    int e = blockIdx.x * blockDim.x + threadIdx.x;
    if (e >= nE) return;
    int r = blockIdx.x & (NREP - 1);
    atomicAdd(&degR[(size_t)r * N + src[e]], w[e]);
    atomicAdd(&cntR[(size_t)r * N + dst[e]], 1);
}

// reduce replicas: dinv[n] = rsqrt(sum deg), cnt[n] = sum cnt
__global__ void k_reduce(const float* __restrict__ degR, const int* __restrict__ cntR,
                         float* __restrict__ dinv, int* __restrict__ cnt, int N) {
    int n = blockIdx.x * blockDim.x + threadIdx.x;
    if (n >= N) return;
    float d = 0.f;
    int c = 0;
#pragma unroll
    for (int r = 0; r < NREP; ++r) {
        d += degR[(size_t)r * N + n];
        c += cntR[(size_t)r * N + n];
    }
    dinv[n] = d > 0.f ? rsqrtf(d) : 0.f;
    cnt[n] = c;
}

// block-local exclusive scan of cnt -> rowptr, block sums -> partials
__global__ void k_scanA(const int* __restrict__ cnt, int* __restrict__ rowptr,
                        int* __restrict__ partials, int N) {
    __shared__ int s[NT];
    int t = threadIdx.x, i = blockIdx.x * NT + t;
    int v = (i < N) ? cnt[i] : 0;
    s[t] = v;
    __syncthreads();
    for (int off = 1; off < NT; off <<= 1) {
        int u = (t >= off) ? s[t - off] : 0;
        __syncthreads();
        s[t] += u;
        __syncthreads();
    }
    if (i < N) rowptr[i] = s[t] - v;
    if (t == NT - 1) partials[blockIdx.x] = s[t];
}

__global__ void k_scanB(int* __restrict__ partials, int nb) {
    __shared__ int s[1024];
    int t = threadIdx.x;
    int v = (t < nb) ? partials[t] : 0;
    s[t] = v;
    __syncthreads();
    for (int off = 1; off < 1024; off <<= 1) {
        int u = (t >= off) ? s[t - off] : 0;
        __syncthreads();
        s[t] += u;
        __syncthreads();
    }
    if (t < nb) partials[t] = s[t] - v;
}

__global__ void k_scanC(int* __restrict__ rowptr, const int* __restrict__ partials,
                        int* __restrict__ cursor, int N) {
    int i = blockIdx.x * NT + threadIdx.x;
    if (i >= N) return;
    int v = rowptr[i] + partials[blockIdx.x];
    rowptr[i] = v;
    cursor[i] = v;
}

// place {src, norm} entries into dst-grouped CSR slots (int atomics only)
__global__ void k_fill(const int* __restrict__ src, const int* __restrict__ dst,
                       const float* __restrict__ w, const float* __restrict__ dinv,
                       int* __restrict__ cursor, int2* __restrict__ entries, int nE) {
    int e = blockIdx.x * blockDim.x + threadIdx.x;
    if (e >= nE) return;
    int s = src[e], d = dst[e];
    float nv = -dinv[s] * w[e] * dinv[d];
    int pos = atomicAdd(&cursor[d], 1);
    entries[pos] = make_int2(s, __float_as_int(nv));
}

__device__ __forceinline__ float4 ld4(const float* p) {
    return *reinterpret_cast<const float4*>(p);
}
__device__ __forceinline__ void fma4(float4& a, float t, const float4& w) {
    a.x = fmaf(t, w.x, a.x); a.y = fmaf(t, w.y, a.y);
    a.z = fmaf(t, w.z, a.z); a.w = fmaf(t, w.w, a.w);
}
__device__ __forceinline__ void fma4s(float4& a, float s, const float4& v) {
    a.x = fmaf(s, v.x, a.x); a.y = fmaf(s, v.y, a.y);
    a.z = fmaf(s, v.z, a.z); a.w = fmaf(s, v.w, a.w);
}

// Tx[n][f4] = scale * sum_e norm_e * t[src_e][f4] - sub[n][f4]; 8 threads/node
__global__ __launch_bounds__(256)
void k_gather(const float* __restrict__ t, const float* __restrict__ sub,
              float* __restrict__ out, const int* __restrict__ rowptr,
              const int* __restrict__ cnt, const int2* __restrict__ entries,
              float scale, int N) {
    int idx = blockIdx.x * blockDim.x + threadIdx.x;
    if (idx >= N * 8) return;
    int n = idx >> 3, q = idx & 7;
    int beg = rowptr[n], end = beg + cnt[n];
    float4 acc0 = make_float4(0, 0, 0, 0), acc1 = make_float4(0, 0, 0, 0);
    int i = beg;
    for (; i + 1 < end; i += 2) {
        int2 e0 = entries[i];
        int2 e1 = entries[i + 1];
        float4 v0 = ld4(t + (size_t)e0.x * 32 + q * 4);
        float4 v1 = ld4(t + (size_t)e1.x * 32 + q * 4);
        fma4s(acc0, __int_as_float(e0.y), v0);
        fma4s(acc1, __int_as_float(e1.y), v1);
    }
    if (i < end) {
        int2 e0 = entries[i];
        fma4s(acc0, __int_as_float(e0.y), ld4(t + (size_t)e0.x * 32 + q * 4));
    }
    float4 r = make_float4(scale * (acc0.x + acc1.x), scale * (acc0.y + acc1.y),
                           scale * (acc0.z + acc1.z), scale * (acc0.w + acc1.w));
    if (sub) {
        float4 s4 = ld4(sub + (size_t)n * 32 + q * 4);
        r.x -= s4.x; r.y -= s4.y; r.z -= s4.z; r.w -= s4.w;
    }
    *reinterpret_cast<float4*>(out + (size_t)n * 32 + q * 4) = r;
}

__device__ __forceinline__ float redfs(float v) {
    v += __shfl_xor(v, 16); v += __shfl_xor(v, 32); return v;
}
__device__ __forceinline__ float4 redfs4(float4 v) {
    v.x = redfs(v.x); v.y = redfs(v.y); v.z = redfs(v.z); v.w = redfs(v.w); return v;
}
__device__ __forceinline__ float4 add4(float4 a, float4 b) {
    return make_float4(a.x + b.x, a.y + b.y, a.z + b.z, a.w + b.w);
}
__device__ __forceinline__ float sigf(float x) {
    return __builtin_amdgcn_rcpf(1.f + __builtin_amdgcn_exp2f(-1.4426950408889634f * x));
}
__device__ __forceinline__ float tanhf_fast(float x) {
    float e = __builtin_amdgcn_exp2f(2.8853900817779268f * x);
    return 1.f - 2.f * __builtin_amdgcn_rcpf(e + 1.f);
}
__device__ __forceinline__ float sel(float4 v, int g) {
    float r = v.x;
    r = (g == 1) ? v.y : r;
    r = (g == 2) ? v.z : r;
    r = (g == 3) ? v.w : r;
    return r;
}

// Fused gates GEMM + LSTM pointwise + linear head.
// Block = 256 threads (4 waves), 64 nodes/block (16 per wave).
// Lane: fs = lane>>4 (f-slice), hq = lane&15 (h-quad). Weight prefetch per cb.
#define JW 16
__global__ __launch_bounds__(256)
void k_final(const float* __restrict__ tx0, const float* __restrict__ tx1,
             const float* __restrict__ tx2, const float* __restrict__ tx3,
             const float* __restrict__ Wx, const float* __restrict__ bx,
             const float* __restrict__ bh, const float* __restrict__ wc,
             const float* __restrict__ bg, const float* __restrict__ lin_w,
             const float* __restrict__ lin_b, float* __restrict__ out, int N) {
    __shared__ float rows[64][128];
    const int tid = threadIdx.x;
    const int base = blockIdx.x * 64;

    for (int i = tid; i < 64 * 128; i += 256) {
        int nl = i >> 7, f = i & 127;
        int n = base + nl;
        float v = 0.f;
        if (n < N) {
            int f5 = f >> 5;
            const float* bp = (f5 == 0) ? tx0 : (f5 == 1) ? tx1 : (f5 == 2) ? tx2 : tx3;
            v = bp[(size_t)n * 32 + (f & 31)];
        }
        rows[nl][f] = v;
    }
    __syncthreads();

    const int wave = tid >> 6, lane = tid & 63;
    const int fs = lane >> 4, hq = lane & 15;
    const float* WI = Wx + 0 * 8192;
    const float* WC = Wx + 2 * 8192;
    const float* WO = Wx + 3 * 8192;
    const int nrow = wave * JW;

    float4 accI[JW], accC[JW], accO[JW];
#pragma unroll
    for (int j = 0; j < JW; ++j) {
        accI[j] = make_float4(0, 0, 0, 0);
        accC[j] = make_float4(0, 0, 0, 0);
        accO[j] = make_float4(0, 0, 0, 0);
    }

    // prefetched-weight main loop over 32 cb (f = cb*4 + fs)
    int wo = (0 * 4 + fs) * 64 + hq * 4;
    float4 wi = ld4(WI + wo), wcg = ld4(WC + wo), wog = ld4(WO + wo);
    for (int cb = 0; cb < 32; ++cb) {
        float4 wiN, wcgN, wogN;
        if (cb < 31) {
            int woN = ((cb + 1) * 4 + fs) * 64 + hq * 4;
            wiN = ld4(WI + woN); wcgN = ld4(WC + woN); wogN = ld4(WO + woN);
        }
        int f = cb * 4 + fs;
#pragma unroll
        for (int j = 0; j < JW; ++j) {
            float t = rows[nrow + j][f];
            fma4(accI[j], t, wi);
            fma4(accC[j], t, wcg);
            fma4(accO[j], t, wog);
        }
        if (cb < 31) { wi = wiN; wcg = wcgN; wog = wogN; }
    }

    const int ho = hq * 4;
    const float bI = sel(add4(add4(ld4(bx + 0 * 64 + ho), ld4(bh + 0 * 64 + ho)),
                              ld4(bg + 0 * 64 + ho)), fs);
    const float bC = sel(add4(add4(ld4(bx + 2 * 64 + ho), ld4(bh + 2 * 64 + ho)),
                              ld4(bg + 2 * 64 + ho)), fs);
    const float bO = sel(add4(add4(ld4(bx + 3 * 64 + ho), ld4(bh + 3 * 64 + ho)),
                              ld4(bg + 3 * 64 + ho)), fs);
    const float wc2s = sel(ld4(wc + 2 * 64 + ho), fs);
    const float lws = sel(ld4(lin_w + ho), fs);
    const float lb = lin_b[0];

#pragma unroll
    for (int j = 0; j < JW; ++j) {
        float ai = sel(redfs4(accI[j]), fs);
        float ac = sel(redfs4(accC[j]), fs);
        float ao = sel(redfs4(accO[j]), fs);

        float I = sigf(ai + bI);
        float T = tanhf_fast(ac + bC);
        float C = I * T;
        float O = sigf(ao + bO + wc2s * C);
        float H = O * tanhf_fast(C);

        float p = H * lws;
        p += __shfl_xor(p, 1);
        p += __shfl_xor(p, 2);
        p += __shfl_xor(p, 4);
        p += __shfl_xor(p, 8);
        p += __shfl_xor(p, 16);
        p += __shfl_xor(p, 32);
        int n = base + nrow + j;
        if (lane == 0 && n < N) out[n] = p + lb;
    }
}

extern "C" void kernel_launch(void* const* d_in, const int* in_sizes, int n_in,
                              void* d_out, int out_size, void* d_ws, size_t ws_size,
                              hipStream_t stream) {
    const float* x   = (const float*)d_in[0];
    const int*   ei  = (const int*)d_in[1];
    const float* ew  = (const float*)d_in[2];
    const float* Wx  = (const float*)d_in[3];
    const float* bx  = (const float*)d_in[4];
    // d_in[5] = Wh (unused: zero initial state)
    const float* bh  = (const float*)d_in[6];
    const float* wcp = (const float*)d_in[7];
    const float* bg  = (const float*)d_in[8];
    const float* lw  = (const float*)d_in[9];
    const float* lb  = (const float*)d_in[10];
    float* out = (float*)d_out;

    const int N  = in_sizes[0] / 32;
    const int nE = in_sizes[2];
    const int* src = ei;
    const int* dst = ei + nE;

    char* ws = (char*)d_ws;
    size_t off = 0;
    float* dinv    = (float*)(ws + off); off += (size_t)N * 4;
    int*   cnt     = (int*)(ws + off);   off += (size_t)N * 4;
    int*   rowptr  = (int*)(ws + off);   off += (size_t)N * 4;
    int*   cursor  = (int*)(ws + off);   off += (size_t)N * 4;
    int*   partials= (int*)(ws + off);   off += 1024 * 4;
    int2*  entries = (int2*)(ws + off);  off += (size_t)nE * 8;
    float* Tx1     = (float*)(ws + off); off += (size_t)N * 32 * 4;
    float* Tx2     = (float*)(ws + off); off += (size_t)N * 32 * 4;
    float* Tx3     = (float*)(ws + off); off += (size_t)N * 32 * 4;

    // replicas alias Tx1/Tx2 (dead before gathers overwrite them)
    float* degR = Tx1;          // NREP * N floats
    int*   cntR = (int*)Tx2;    // NREP * N ints

    hipMemsetAsync(degR, 0, (size_t)NREP * N * 4, stream);
    hipMemsetAsync(cntR, 0, (size_t)NREP * N * 4, stream);

    const int eb = (nE + NT - 1) / NT;
    const int nb = (N + NT - 1) / NT;

    k_deg_hist<<<eb, NT, 0, stream>>>(src, dst, ew, degR, cntR, nE, N);
    k_reduce<<<nb, NT, 0, stream>>>(degR, cntR, dinv, cnt, N);
    k_scanA<<<nb, NT, 0, stream>>>(cnt, rowptr, partials, N);
    k_scanB<<<1, 1024, 0, stream>>>(partials, nb);
    k_scanC<<<nb, NT, 0, stream>>>(rowptr, partials, cursor, N);
    k_fill<<<eb, NT, 0, stream>>>(src, dst, ew, dinv, cursor, entries, nE);

    const int gb = (N * 8 + NT - 1) / NT;
    k_gather<<<gb, NT, 0, stream>>>(x,   nullptr, Tx1, rowptr, cnt, entries, 1.f, N);
    k_gather<<<gb, NT, 0, stream>>>(Tx1, x,       Tx2, rowptr, cnt, entries, 2.f, N);
    k_gather<<<gb, NT, 0, stream>>>(Tx2, Tx1,     Tx3, rowptr, cnt, entries, 2.f, N);

    const int fb = (N + 63) / 64;
    k_final<<<fb, NT, 0, stream>>>(x, Tx1, Tx2, Tx3, Wx, bx, bh, wcp, bg,
                                   lw, lb, out, N);
}

// Round 5
// 223.790 us; speedup vs baseline: 5.0422x; 1.1479x over previous
//
#include <hip/hip_runtime.h>
#include <math.h>

// GConvLSTM single step from zero state + linear head.
// H=C=0 initially => cheb_conv(H)=bh[g], F-gate irrelevant.
//   I = sigmoid(chebX_0 + bx0+bh0+bg0)
//   T = tanh   (chebX_2 + bx2+bh2+bg2)
//   C = I*T
//   O = sigmoid(chebX_3 + bx3+bh3+bg3 + wc2*C)
//   out = (O*tanh(C)) @ lin_w + lin_b
//
// R2: push->pull CSR gather (no float atomics).
// R3: hw transcendentals.
// R4: 8-replica deg/cnt histograms; float4 gather.
// R5: k_final lane=h restructure (24 scalar accs, no cross-lane reduce,
//     prepacked coalesced W float4 loads, broadcast ds_read_b128 for T);
//     k_gather 4-deep entry/feature unroll to cut dependent-chain latency.

#define NT 256
#define NREP 8

__global__ void k_deg_hist(const int* __restrict__ src, const int* __restrict__ dst,
                           const float* __restrict__ w, float* __restrict__ degR,
                           int* __restrict__ cntR, int nE, int N) {
    int e = blockIdx.x * blockDim.x + threadIdx.x;
    if (e >= nE) return;
    int r = blockIdx.x & (NREP - 1);
    atomicAdd(&degR[(size_t)r * N + src[e]], w[e]);
    atomicAdd(&cntR[(size_t)r * N + dst[e]], 1);
}

// reduce replicas: dinv[n] = rsqrt(sum deg), cnt[n] = sum cnt
__global__ void k_reduce(const float* __restrict__ degR, const int* __restrict__ cntR,
                         float* __restrict__ dinv, int* __restrict__ cnt, int N) {
    int n = blockIdx.x * blockDim.x + threadIdx.x;
    if (n >= N) return;
    float d = 0.f;
    int c = 0;
#pragma unroll
    for (int r = 0; r < NREP; ++r) {
        d += degR[(size_t)r * N + n];
        c += cntR[(size_t)r * N + n];
    }
    dinv[n] = d > 0.f ? rsqrtf(d) : 0.f;
    cnt[n] = c;
}

__global__ void k_scanA(const int* __restrict__ cnt, int* __restrict__ rowptr,
                        int* __restrict__ partials, int N) {
    __shared__ int s[NT];
    int t = threadIdx.x, i = blockIdx.x * NT + t;
    int v = (i < N) ? cnt[i] : 0;
    s[t] = v;
    __syncthreads();
    for (int off = 1; off < NT; off <<= 1) {
        int u = (t >= off) ? s[t - off] : 0;
        __syncthreads();
        s[t] += u;
        __syncthreads();
    }
    if (i < N) rowptr[i] = s[t] - v;
    if (t == NT - 1) partials[blockIdx.x] = s[t];
}

__global__ void k_scanB(int* __restrict__ partials, int nb) {
    __shared__ int s[1024];
    int t = threadIdx.x;
    int v = (t < nb) ? partials[t] : 0;
    s[t] = v;
    __syncthreads();
    for (int off = 1; off < 1024; off <<= 1) {
        int u = (t >= off) ? s[t - off] : 0;
        __syncthreads();
        s[t] += u;
        __syncthreads();
    }
    if (t < nb) partials[t] = s[t] - v;
}

__global__ void k_scanC(int* __restrict__ rowptr, const int* __restrict__ partials,
                        int* __restrict__ cursor, int N) {
    int i = blockIdx.x * NT + threadIdx.x;
    if (i >= N) return;
    int v = rowptr[i] + partials[blockIdx.x];
    rowptr[i] = v;
    cursor[i] = v;
}

__global__ void k_fill(const int* __restrict__ src, const int* __restrict__ dst,
                       const float* __restrict__ w, const float* __restrict__ dinv,
                       int* __restrict__ cursor, int2* __restrict__ entries, int nE) {
    int e = blockIdx.x * blockDim.x + threadIdx.x;
    if (e >= nE) return;
    int s = src[e], d = dst[e];
    float nv = -dinv[s] * w[e] * dinv[d];
    int pos = atomicAdd(&cursor[d], 1);
    entries[pos] = make_int2(s, __float_as_int(nv));
}

__device__ __forceinline__ float4 ld4(const float* p) {
    return *reinterpret_cast<const float4*>(p);
}
__device__ __forceinline__ void fma4s(float4& a, float s, const float4& v) {
    a.x = fmaf(s, v.x, a.x); a.y = fmaf(s, v.y, a.y);
    a.z = fmaf(s, v.z, a.z); a.w = fmaf(s, v.w, a.w);
}

// Tx[n][f4] = scale * sum_e norm_e * t[src_e][f4] - sub[n][f4]; 8 threads/node.
// 4-deep unroll: 4 entry loads then 4 independent feature loads in flight.
__global__ __launch_bounds__(256)
void k_gather(const float* __restrict__ t, const float* __restrict__ sub,
              float* __restrict__ out, const int* __restrict__ rowptr,
              const int* __restrict__ cnt, const int2* __restrict__ entries,
              float scale, int N) {
    int idx = blockIdx.x * blockDim.x + threadIdx.x;
    if (idx >= N * 8) return;
    int n = idx >> 3, q = idx & 7;
    int beg = rowptr[n], end = beg + cnt[n];
    float4 acc0 = make_float4(0, 0, 0, 0), acc1 = make_float4(0, 0, 0, 0);
    float4 acc2 = make_float4(0, 0, 0, 0), acc3 = make_float4(0, 0, 0, 0);
    int i = beg;
    for (; i + 3 < end; i += 4) {
        int2 e0 = entries[i];
        int2 e1 = entries[i + 1];
        int2 e2 = entries[i + 2];
        int2 e3 = entries[i + 3];
        float4 v0 = ld4(t + (size_t)e0.x * 32 + q * 4);
        float4 v1 = ld4(t + (size_t)e1.x * 32 + q * 4);
        float4 v2 = ld4(t + (size_t)e2.x * 32 + q * 4);
        float4 v3 = ld4(t + (size_t)e3.x * 32 + q * 4);
        fma4s(acc0, __int_as_float(e0.y), v0);
        fma4s(acc1, __int_as_float(e1.y), v1);
        fma4s(acc2, __int_as_float(e2.y), v2);
        fma4s(acc3, __int_as_float(e3.y), v3);
    }
    for (; i < end; ++i) {
        int2 e0 = entries[i];
        fma4s(acc0, __int_as_float(e0.y), ld4(t + (size_t)e0.x * 32 + q * 4));
    }
    acc0.x += acc1.x + acc2.x + acc3.x;
    acc0.y += acc1.y + acc2.y + acc3.y;
    acc0.z += acc1.z + acc2.z + acc3.z;
    acc0.w += acc1.w + acc2.w + acc3.w;
    float4 r = make_float4(scale * acc0.x, scale * acc0.y, scale * acc0.z, scale * acc0.w);
    if (sub) {
        float4 s4 = ld4(sub + (size_t)n * 32 + q * 4);
        r.x -= s4.x; r.y -= s4.y; r.z -= s4.z; r.w -= s4.w;
    }
    *reinterpret_cast<float4*>(out + (size_t)n * 32 + q * 4) = r;
}

// pre-pack gate weights: P[((k4*3+g)*64+h)*4 + kk] = Wgate[(k4*4+kk)*64 + h]
// g: 0->Wx gate0 (I), 1->gate2 (C), 2->gate3 (O)
__global__ void k_prepack(const float* __restrict__ Wx, float* __restrict__ P) {
    int idx = blockIdx.x * blockDim.x + threadIdx.x;
    if (idx >= 32 * 3 * 64) return;
    int h = idx & 63;
    int g = (idx >> 6) % 3;
    int k4 = idx / 192;
    const int gate = (g == 0) ? 0 : (g == 1) ? 2 : 3;
    const float* W = Wx + gate * 8192;
    float4 v;
    v.x = W[(k4 * 4 + 0) * 64 + h];
    v.y = W[(k4 * 4 + 1) * 64 + h];
    v.z = W[(k4 * 4 + 2) * 64 + h];
    v.w = W[(k4 * 4 + 3) * 64 + h];
    *reinterpret_cast<float4*>(P + (size_t)idx * 4) = v;
}

__device__ __forceinline__ float sigf(float x) {
    return __builtin_amdgcn_rcpf(1.f + __builtin_amdgcn_exp2f(-1.4426950408889634f * x));
}
__device__ __forceinline__ float tanhf_fast(float x) {
    float e = __builtin_amdgcn_exp2f(2.8853900817779268f * x);
    return 1.f - 2.f * __builtin_amdgcn_rcpf(e + 1.f);
}
__device__ __forceinline__ float dot4(float4 a, float4 b, float acc) {
    return fmaf(a.x, b.x, fmaf(a.y, b.y, fmaf(a.z, b.z, fmaf(a.w, b.w, acc))));
}

// Fused gates GEMM + LSTM pointwise + linear head.
// lane = h (64 hidden). Wave owns 8 nodes; block (4 waves) owns 32 nodes.
// acc = 3 gates x 8 nodes scalar VGPRs. W via prepacked coalesced float4.
__global__ __launch_bounds__(256)
void k_final(const float* __restrict__ tx0, const float* __restrict__ tx1,
             const float* __restrict__ tx2, const float* __restrict__ tx3,
             const float* __restrict__ P, const float* __restrict__ bx,
             const float* __restrict__ bh, const float* __restrict__ wc,
             const float* __restrict__ bg, const float* __restrict__ lin_w,
             const float* __restrict__ lin_b, float* __restrict__ out, int N) {
    __shared__ float rows[32][128];
    const int tid = threadIdx.x;
    const int base = blockIdx.x * 32;

    // stage 32 nodes x 128 feats as float4 (coalesced)
    for (int i = tid; i < 32 * 32; i += 256) {
        int nl = i >> 5, f4 = i & 31;
        int n = base + nl;
        float4 v = make_float4(0, 0, 0, 0);
        if (n < N) {
            int f5 = f4 >> 3;
            const float* bp = (f5 == 0) ? tx0 : (f5 == 1) ? tx1 : (f5 == 2) ? tx2 : tx3;
            v = ld4(bp + (size_t)n * 32 + (f4 & 7) * 4);
        }
        *reinterpret_cast<float4*>(&rows[nl][f4 * 4]) = v;
    }
    __syncthreads();

    const int wave = tid >> 6, lane = tid & 63;
    const int nrow = wave * 8;

    float accI[8], accC[8], accO[8];
#pragma unroll
    for (int j = 0; j < 8; ++j) { accI[j] = 0.f; accC[j] = 0.f; accO[j] = 0.f; }

    for (int k4 = 0; k4 < 32; ++k4) {
        const float* Pb = P + (size_t)k4 * 768 + lane * 4;
        float4 wi  = ld4(Pb);
        float4 wcg = ld4(Pb + 256);
        float4 wog = ld4(Pb + 512);
#pragma unroll
        for (int j = 0; j < 8; ++j) {
            float4 tq = ld4(&rows[nrow + j][k4 * 4]);  // broadcast ds_read_b128
            accI[j] = dot4(tq, wi,  accI[j]);
            accC[j] = dot4(tq, wcg, accC[j]);
            accO[j] = dot4(tq, wog, accO[j]);
        }
    }

    // per-lane (h = lane) biases
    const float bI = bx[lane] + bh[lane] + bg[lane];
    const float bC = bx[128 + lane] + bh[128 + lane] + bg[128 + lane];
    const float bO = bx[192 + lane] + bh[192 + lane] + bg[192 + lane];
    const float wc2s = wc[128 + lane];
    const float lws = lin_w[lane];
    const float lb = lin_b[0];

#pragma unroll
    for (int j = 0; j < 8; ++j) {
        float I = sigf(accI[j] + bI);
        float T = tanhf_fast(accC[j] + bC);
        float C = I * T;
        float O = sigf(accO[j] + bO + wc2s * C);
        float H = O * tanhf_fast(C);

        float p = H * lws;
        p += __shfl_xor(p, 1);
        p += __shfl_xor(p, 2);
        p += __shfl_xor(p, 4);
        p += __shfl_xor(p, 8);
        p += __shfl_xor(p, 16);
        p += __shfl_xor(p, 32);
        int n = base + nrow + j;
        if (lane == 0 && n < N) out[n] = p + lb;
    }
}

extern "C" void kernel_launch(void* const* d_in, const int* in_sizes, int n_in,
                              void* d_out, int out_size, void* d_ws, size_t ws_size,
                              hipStream_t stream) {
    const float* x   = (const float*)d_in[0];
    const int*   ei  = (const int*)d_in[1];
    const float* ew  = (const float*)d_in[2];
    const float* Wx  = (const float*)d_in[3];
    const float* bx  = (const float*)d_in[4];
    // d_in[5] = Wh (unused: zero initial state)
    const float* bh  = (const float*)d_in[6];
    const float* wcp = (const float*)d_in[7];
    const float* bg  = (const float*)d_in[8];
    const float* lw  = (const float*)d_in[9];
    const float* lb  = (const float*)d_in[10];
    float* out = (float*)d_out;

    const int N  = in_sizes[0] / 32;
    const int nE = in_sizes[2];
    const int* src = ei;
    const int* dst = ei + nE;

    char* ws = (char*)d_ws;
    size_t off = 0;
    float* dinv    = (float*)(ws + off); off += (size_t)N * 4;
    int*   cnt     = (int*)(ws + off);   off += (size_t)N * 4;
    int*   rowptr  = (int*)(ws + off);   off += (size_t)N * 4;
    int*   cursor  = (int*)(ws + off);   off += (size_t)N * 4;
    int*   partials= (int*)(ws + off);   off += 1024 * 4;
    float* P       = (float*)(ws + off); off += 32 * 3 * 64 * 4 * 4;
    int2*  entries = (int2*)(ws + off);  off += (size_t)nE * 8;
    float* Tx1     = (float*)(ws + off); off += (size_t)N * 32 * 4;
    float* Tx2     = (float*)(ws + off); off += (size_t)N * 32 * 4;
    float* Tx3     = (float*)(ws + off); off += (size_t)N * 32 * 4;

    // replicas alias Tx1/Tx2 (dead before gathers overwrite them)
    float* degR = Tx1;          // NREP * N floats
    int*   cntR = (int*)Tx2;    // NREP * N ints

    hipMemsetAsync(degR, 0, (size_t)NREP * N * 4, stream);
    hipMemsetAsync(cntR, 0, (size_t)NREP * N * 4, stream);

    const int eb = (nE + NT - 1) / NT;
    const int nb = (N + NT - 1) / NT;

    k_deg_hist<<<eb, NT, 0, stream>>>(src, dst, ew, degR, cntR, nE, N);
    k_prepack<<<(32 * 3 * 64 + NT - 1) / NT, NT, 0, stream>>>(Wx, P);
    k_reduce<<<nb, NT, 0, stream>>>(degR, cntR, dinv, cnt, N);
    k_scanA<<<nb, NT, 0, stream>>>(cnt, rowptr, partials, N);
    k_scanB<<<1, 1024, 0, stream>>>(partials, nb);
    k_scanC<<<nb, NT, 0, stream>>>(rowptr, partials, cursor, N);
    k_fill<<<eb, NT, 0, stream>>>(src, dst, ew, dinv, cursor, entries, nE);

    const int gb = (N * 8 + NT - 1) / NT;
    k_gather<<<gb, NT, 0, stream>>>(x,   nullptr, Tx1, rowptr, cnt, entries, 1.f, N);
    k_gather<<<gb, NT, 0, stream>>>(Tx1, x,       Tx2, rowptr, cnt, entries, 2.f, N);
    k_gather<<<gb, NT, 0, stream>>>(Tx2, Tx1,     Tx3, rowptr, cnt, entries, 2.f, N);

    const int fb = (N + 31) / 32;
    k_final<<<fb, NT, 0, stream>>>(x, Tx1, Tx2, Tx3, P, bx, bh, wcp, bg,
                                   lw, lb, out, N);
}